// Round 5
// baseline (853.945 us; speedup 1.0000x reference)
//
#include <hip/hip_runtime.h>

typedef _Float16 f16;
typedef _Float16 f16x2 __attribute__((ext_vector_type(2)));
typedef _Float16 f16x8 __attribute__((ext_vector_type(8)));
typedef float f32x4 __attribute__((ext_vector_type(4)));

// d_out h-region: row r owns bytes [r*1024, (r+1)*1024)  (256 fp32 per row).
// Scratch slots while pipeline runs:
//   [0,256)    AGG (f16[128])
//   [256,512)  SA  (f16[128])
//   [512,768)  SB  (f16[128])
//   [768,1024) ADJ (int[64])  -- CSR adjacency, element i at row i>>6, word i&63
// Final GEMM overwrites full rows with 256 fp32; edges written after h region.
#define ROWB 1024
#define OFF_AGG 0
#define OFF_SA 256
#define OFF_SB 512
#define OFF_ADJ 768

__device__ __forceinline__ float bf2f(unsigned short h) {
  return __uint_as_float(((unsigned)h) << 16);
}
__device__ __forceinline__ unsigned short f2bf(float f) {
  unsigned u = __float_as_uint(f);
  u += 0x7fffu + ((u >> 16) & 1u);
  return (unsigned short)(u >> 16);
}
// NaN -> 0, clamp to f16-safe range: guarantees finite stores.
__device__ __forceinline__ float scrub(float v) {
  if (!(v == v)) return 0.f;
  return fminf(fmaxf(v, -65504.f), 65504.f);
}
__device__ __forceinline__ int iclamp(int v, int lo, int hi) {
  return v < lo ? lo : (v > hi ? hi : v);
}

__device__ __forceinline__ int adj_read(const char* H, int i) {
  return *(const int*)(H + ((size_t)(i >> 6)) * ROWB + OFF_ADJ + (i & 63) * 4);
}
__device__ __forceinline__ void adj_write(char* H, int i, int v) {
  *(int*)(H + ((size_t)(i >> 6)) * ROWB + OFF_ADJ + (i & 63) * 4) = v;
}

// ---- detect edge_index width: int64 => odd int32 words (high halves) all zero ----
__global__ __launch_bounds__(64) void k_detect(const int* __restrict__ ei,
                                               int* __restrict__ flag) {
  int lane = threadIdx.x;
  int v = ei[2 * lane + 1];
  unsigned long long m = __ballot(v == 0);
  if (lane == 0) *flag = (m == 0xFFFFFFFFFFFFFFFFull) ? 1 : 0;  // 1 = int64
}

// ---- degree histogram ----
__global__ __launch_bounds__(256) void k_degree(const int* __restrict__ ei, int E, int n,
                                                const int* __restrict__ flag,
                                                unsigned* __restrict__ dego,
                                                unsigned* __restrict__ degi) {
  int e = blockIdx.x * 256 + threadIdx.x;
  if (e >= E) return;
  int sh = *flag;
  int s = ei[(size_t)e << sh];
  int d = ei[((size_t)E << sh) + ((size_t)e << sh)];
  atomicAdd(&dego[iclamp(s, 0, n - 1)], 1u);
  atomicAdd(&degi[iclamp(d, 0, n - 1)], 1u);
}

// ---- scan 1: per-block sums ----
__global__ __launch_bounds__(256) void k_scan1(const int* __restrict__ deg, int n,
                                               int* __restrict__ bsum) {
  __shared__ int sh[256];
  int tid = threadIdx.x;
  int i = blockIdx.x * 256 + tid;
  sh[tid] = (i < n) ? deg[i] : 0;
  __syncthreads();
  for (int s = 128; s > 0; s >>= 1) {
    if (tid < s) sh[tid] += sh[tid + s];
    __syncthreads();
  }
  if (tid == 0) bsum[blockIdx.x] = sh[0];
}

// ---- scan 2: exclusive scan of block sums (nb<=512) ----
__global__ __launch_bounds__(512) void k_scan2(int* __restrict__ bsum, int nb,
                                               int* __restrict__ total_out) {
  __shared__ int sh[512];
  int tid = threadIdx.x;
  int v = (tid < nb) ? bsum[tid] : 0;
  sh[tid] = v;
  __syncthreads();
  for (int off = 1; off < 512; off <<= 1) {
    int t = (tid >= off) ? sh[tid - off] : 0;
    __syncthreads();
    sh[tid] += t;
    __syncthreads();
  }
  if (tid < nb) bsum[tid] = sh[tid] - v;
  if (tid == 0) *total_out = sh[511];
}

// ---- scan 3: rowptr ----
__global__ __launch_bounds__(256) void k_scan3(const int* __restrict__ deg,
                                               const int* __restrict__ bsum,
                                               int* __restrict__ rowptr, int n) {
  __shared__ int sh[256];
  int tid = threadIdx.x;
  int i = blockIdx.x * 256 + tid;
  int v = (i < n) ? deg[i] : 0;
  sh[tid] = v;
  __syncthreads();
  for (int off = 1; off < 256; off <<= 1) {
    int t = (tid >= off) ? sh[tid - off] : 0;
    __syncthreads();
    sh[tid] += t;
    __syncthreads();
  }
  if (i < n) rowptr[i] = bsum[blockIdx.x] + sh[tid] - v;
}

// ---- degree counts -> rsqrt norms ----
__global__ __launch_bounds__(256) void k_norm(unsigned* __restrict__ dego,
                                              unsigned* __restrict__ degi, int n) {
  int i = blockIdx.x * 256 + threadIdx.x;
  if (i >= n) return;
  unsigned a = dego[i];
  dego[i] = __float_as_uint(a ? rsqrtf((float)a) : 0.f);
  unsigned b = degi[i];
  degi[i] = __float_as_uint(b ? rsqrtf((float)b) : 0.f);
}

// ---- CSR fill into d_out ADJ slots ----
__global__ __launch_bounds__(256) void k_fill(const int* __restrict__ ei, int E, int n,
                                              const int* __restrict__ flag,
                                              const int* __restrict__ rowptr,
                                              unsigned* __restrict__ cursor,
                                              char* __restrict__ H) {
  int e = blockIdx.x * 256 + threadIdx.x;
  if (e >= E) return;
  int sh = *flag;
  int s = iclamp(ei[(size_t)e << sh], 0, n - 1);
  int d = iclamp(ei[((size_t)E << sh) + ((size_t)e << sh)], 0, n - 1);
  unsigned slot = atomicAdd(&cursor[d], 1u);
  int idx = iclamp(rowptr[d] + (int)slot, 0, E - 1);
  adj_write(H, idx, s);
}

// ---- S = fp32 x * norm_src -> f16 (SB slot). X is fp32 [n,128]; thread = 2 elems ----
__global__ __launch_bounds__(256) void k_scale_x(const float* __restrict__ X,
                                                 const unsigned* __restrict__ nsrc,
                                                 char* __restrict__ Sc, int n64) {
  int i = blockIdx.x * 256 + threadIdx.x;
  if (i >= n64) return;
  int r = i >> 6, c = i & 63;
  float ns = __uint_as_float(nsrc[r]);
  float2 v = ((const float2*)X)[i];
  f16x2 o;
  o[0] = (f16)scrub(v.x * ns);
  o[1] = (f16)scrub(v.y * ns);
  *(f16x2*)(Sc + (size_t)r * ROWB + c * 4) = o;
}

// ---- one wave per dst row: out[row] = nd[row] * sum_{j in adj(row)} Sin[j] ----
__global__ __launch_bounds__(256) void k_aggregate(const char* __restrict__ H,
                                                   int sinOff, int outOff,
                                                   const int* __restrict__ rowptr,
                                                   const unsigned* __restrict__ ndst,
                                                   int n, int E) {
  int gw = (int)((blockIdx.x * 256u + threadIdx.x) >> 6);
  int lane = threadIdx.x & 63;
  if (gw >= n) return;
  int s = iclamp(rowptr[gw], 0, E);
  int e = iclamp(rowptr[gw + 1], s, E);
  const char* Sin = H + sinOff;
  float a0 = 0.f, a1 = 0.f;
  int i = s;
  for (; i + 2 <= e; i += 2) {
    int s0 = iclamp(adj_read(H, i), 0, n - 1);
    int s1 = iclamp(adj_read(H, i + 1), 0, n - 1);
    f16x2 v0 = *(const f16x2*)(Sin + (size_t)s0 * ROWB + lane * 4);
    f16x2 v1 = *(const f16x2*)(Sin + (size_t)s1 * ROWB + lane * 4);
    a0 += (float)v0[0] + (float)v1[0];
    a1 += (float)v0[1] + (float)v1[1];
  }
  if (i < e) {
    int s0 = iclamp(adj_read(H, i), 0, n - 1);
    f16x2 v0 = *(const f16x2*)(Sin + (size_t)s0 * ROWB + lane * 4);
    a0 += (float)v0[0];
    a1 += (float)v0[1];
  }
  float nd = __uint_as_float(ndst[gw]);
  f16x2 o;
  o[0] = (f16)scrub(a0 * nd);
  o[1] = (f16)scrub(a1 * nd);
  *(f16x2*)(((char*)H) + outOff + (size_t)gw * ROWB + lane * 4) = o;
}

// ---- GEMM: C[n,DOUT] = A[n,128] @ W[128,DOUT] + b; A rows strided ROWB (AGG slot).
// W/bias fp32. MID: relu*norm_src -> f16 slot. else: fp32 full row (scrubbed).
template <int DOUT, bool MID>
__global__ __launch_bounds__(256) void k_gemm(const char* __restrict__ A,
                                              const float* __restrict__ W,
                                              const float* __restrict__ bias,
                                              const unsigned* __restrict__ nsrc,
                                              char* __restrict__ OUT, int n) {
  extern __shared__ char smem_raw[];
  f16* sB = (f16*)smem_raw;  // W^T swizzled: [DOUT][128]
  const int tid = threadIdx.x;
  for (int idx = tid; idx < 128 * DOUT; idx += 256) {
    int k = idx / DOUT;
    int nn = idx % DOUT;
    int g = (k >> 3) ^ (nn & 15);
    sB[nn * 128 + (g << 3) + (k & 7)] = (f16)scrub(W[idx]);
  }
  __syncthreads();
  const int wave = tid >> 6, lane = tid & 63;
  const int quad = lane >> 4, l16 = lane & 15;
  const int rowbase = blockIdx.x * 128 + wave * 32;
  constexpr int NT = DOUT / 16;
  f32x4 acc[2][NT] = {};
  int r0 = rowbase + l16;      if (r0 > n - 1) r0 = n - 1;
  int r1 = rowbase + 16 + l16; if (r1 > n - 1) r1 = n - 1;
#pragma unroll
  for (int ks = 0; ks < 4; ++ks) {
    const int k0 = ks * 32 + quad * 8;
    const int kg = ks * 4 + quad;
    f16x8 a0 = *(const f16x8*)(A + (size_t)r0 * ROWB + k0 * 2);
    f16x8 a1 = *(const f16x8*)(A + (size_t)r1 * ROWB + k0 * 2);
#pragma unroll
    for (int nt = 0; nt < NT; ++nt) {
      int nn = nt * 16 + l16;
      f16x8 b = *(const f16x8*)(sB + nn * 128 + ((kg ^ l16) << 3));
      acc[0][nt] = __builtin_amdgcn_mfma_f32_16x16x32_f16(a0, b, acc[0][nt], 0, 0, 0);
      acc[1][nt] = __builtin_amdgcn_mfma_f32_16x16x32_f16(a1, b, acc[1][nt], 0, 0, 0);
    }
  }
#pragma unroll
  for (int mt = 0; mt < 2; ++mt) {
#pragma unroll
    for (int r = 0; r < 4; ++r) {
      int row = rowbase + mt * 16 + quad * 4 + r;
      if (row >= n) continue;
      float ns = MID ? __uint_as_float(nsrc[row]) : 1.f;
#pragma unroll
      for (int nt = 0; nt < NT; ++nt) {
        int col = nt * 16 + l16;
        float v = acc[mt][nt][r] + bias[col];
        if (MID) {
          v = scrub(fmaxf(v, 0.f) * ns);
          *(f16*)(OUT + (size_t)row * ROWB + col * 2) = (f16)v;
        } else {
          *(float*)(OUT + (size_t)row * ROWB + col * 4) = scrub(v);
        }
      }
    }
  }
}

// ---- edge_index passthrough as fp32 (bf16-rounded to match bf16-rounded ref) ----
__global__ __launch_bounds__(256) void k_edges(const int* __restrict__ ei,
                                               const int* __restrict__ flag,
                                               float* __restrict__ out, int m) {
  int i = blockIdx.x * 256 + threadIdx.x;
  if (i >= m) return;
  int sh = *flag;
  int v = ei[(size_t)i << sh];
  out[i] = bf2f(f2bf((float)v));
}

extern "C" void kernel_launch(void* const* d_in, const int* in_sizes, int n_in,
                              void* d_out, int out_size, void* d_ws, size_t ws_size,
                              hipStream_t stream) {
  const float* X = (const float*)d_in[0];                   // fp32 [N,128]
  const int* EI = (const int*)d_in[1];                      // int32 or int64 (detected)
  const float* W1 = (const float*)d_in[2];
  const float* B1 = (const float*)d_in[3];
  const float* W2 = (const float*)d_in[4];
  const float* B2 = (const float*)d_in[5];
  const float* W3 = (const float*)d_in[6];
  const float* B3 = (const float*)d_in[7];

  const int n = in_sizes[0] / 128;   // 100000
  const int E = in_sizes[1] / 2;     // 1600000

  // tiny workspace (~1.7 MB)
  char* w = (char*)d_ws;
  const size_t nb = ((size_t)n * 4 + 1023) & ~(size_t)1023;
  int* flag        = (int*)(w);
  unsigned* dego   = (unsigned*)(w + 1024);
  unsigned* degi   = (unsigned*)(w + 1024 + nb);
  int* rowptr      = (int*)(w + 1024 + 2 * nb);      // n+1 ints
  unsigned* cursor = (unsigned*)(w + 1024 + 3 * nb);
  int* bsum        = (int*)(w + 1024 + 4 * nb);      // <=512 ints

  char* H = (char*)d_out;            // h region: n rows x 1024B (slots + ADJ)

  const int gE = (E + 255) / 256;
  const int gN = (n + 255) / 256;
  const int g64 = (n * 64 + 255) / 256;
  const int gG = (n + 127) / 128;

  hipMemsetAsync(dego, 0, (size_t)n * 4, stream);
  hipMemsetAsync(degi, 0, (size_t)n * 4, stream);
  hipMemsetAsync(cursor, 0, (size_t)n * 4, stream);

  k_detect<<<1, 64, 0, stream>>>(EI, flag);
  k_degree<<<gE, 256, 0, stream>>>(EI, E, n, flag, dego, degi);
  k_scan1<<<gN, 256, 0, stream>>>((const int*)degi, n, bsum);
  k_scan2<<<1, 512, 0, stream>>>(bsum, gN, rowptr + n);
  k_scan3<<<gN, 256, 0, stream>>>((const int*)degi, bsum, rowptr, n);
  k_fill<<<gE, 256, 0, stream>>>(EI, E, n, flag, rowptr, cursor, H);
  k_norm<<<gN, 256, 0, stream>>>(dego, degi, n);

  // layer 1: X -> SB; agg(SB)->AGG; gemm AGG->SA
  k_scale_x<<<g64, 256, 0, stream>>>(X, dego, H + OFF_SB, n * 64);
  k_aggregate<<<g64, 256, 0, stream>>>(H, OFF_SB, OFF_AGG, rowptr, degi, n, E);
  k_gemm<128, true><<<gG, 256, 128 * 128 * 2, stream>>>(H + OFF_AGG, W1, B1, dego,
                                                        H + OFF_SA, n);
  // layer 2: agg(SA)->AGG; gemm AGG->SB
  k_aggregate<<<g64, 256, 0, stream>>>(H, OFF_SA, OFF_AGG, rowptr, degi, n, E);
  k_gemm<128, true><<<gG, 256, 128 * 128 * 2, stream>>>(H + OFF_AGG, W2, B2, dego,
                                                        H + OFF_SB, n);
  // layer 3: agg(SB)->AGG; gemm AGG -> full fp32 rows (block-local read-then-write)
  k_aggregate<<<g64, 256, 0, stream>>>(H, OFF_SB, OFF_AGG, rowptr, degi, n, E);
  k_gemm<256, false><<<gG, 256, 256 * 128 * 2, stream>>>(H + OFF_AGG, W3, B3, dego,
                                                         H, n);

  // edges last
  k_edges<<<(2 * E + 255) / 256, 256, 0, stream>>>(
      EI, flag, (float*)d_out + (size_t)n * 256, 2 * E);
}

// Round 6
// 750.129 us; speedup vs baseline: 1.1384x; 1.1384x over previous
//
#include <hip/hip_runtime.h>

typedef _Float16 f16;
typedef _Float16 f16x2 __attribute__((ext_vector_type(2)));
typedef _Float16 f16x8 __attribute__((ext_vector_type(8)));
typedef float f32x4 __attribute__((ext_vector_type(4)));

// d_out h-region: row r owns bytes [r*1024, (r+1)*1024)  (256 fp32 per row).
// Scratch slots while pipeline runs:
//   [0,256)    AGG (f16[128])
//   [256,512)  SA  (f16[128])
//   [512,768)  SB  (f16[128])
//   [768,1024) ADJ (int[64])  -- CSR adjacency, element i at row i>>6, word i&63
// Final GEMM overwrites full rows with 256 fp32; edges written after h region.
#define ROWB 1024
#define OFF_AGG 0
#define OFF_SA 256
#define OFF_SB 512
#define OFF_ADJ 768

__device__ __forceinline__ float bf2f(unsigned short h) {
  return __uint_as_float(((unsigned)h) << 16);
}
__device__ __forceinline__ unsigned short f2bf(float f) {
  unsigned u = __float_as_uint(f);
  u += 0x7fffu + ((u >> 16) & 1u);
  return (unsigned short)(u >> 16);
}
__device__ __forceinline__ float scrub(float v) {
  if (!(v == v)) return 0.f;
  return fminf(fmaxf(v, -65504.f), 65504.f);
}
__device__ __forceinline__ int iclamp(int v, int lo, int hi) {
  return v < lo ? lo : (v > hi ? hi : v);
}

__device__ __forceinline__ int adj_read(const char* H, int i) {
  return *(const int*)(H + ((size_t)(i >> 6)) * ROWB + OFF_ADJ + (i & 63) * 4);
}
__device__ __forceinline__ void adj_write(char* H, int i, int v) {
  *(int*)(H + ((size_t)(i >> 6)) * ROWB + OFF_ADJ + (i & 63) * 4) = v;
}

// ---- detect edge_index width: int64 => odd int32 words all zero ----
__global__ __launch_bounds__(64) void k_detect(const int* __restrict__ ei,
                                               int* __restrict__ flag) {
  int lane = threadIdx.x;
  int v = ei[2 * lane + 1];
  unsigned long long m = __ballot(v == 0);
  if (lane == 0) *flag = (m == 0xFFFFFFFFFFFFFFFFull) ? 1 : 0;  // 1 = int64
}

// ---- degree histogram ----
__global__ __launch_bounds__(256) void k_degree(const int* __restrict__ ei, int E, int n,
                                                const int* __restrict__ flag,
                                                unsigned* __restrict__ dego,
                                                unsigned* __restrict__ degi) {
  int e = blockIdx.x * 256 + threadIdx.x;
  if (e >= E) return;
  int sh = *flag;
  int s = ei[(size_t)e << sh];
  int d = ei[((size_t)E << sh) + ((size_t)e << sh)];
  atomicAdd(&dego[iclamp(s, 0, n - 1)], 1u);
  atomicAdd(&degi[iclamp(d, 0, n - 1)], 1u);
}

// ---- scan 1: per-block sums ----
__global__ __launch_bounds__(256) void k_scan1(const int* __restrict__ deg, int n,
                                               int* __restrict__ bsum) {
  __shared__ int sh[256];
  int tid = threadIdx.x;
  int i = blockIdx.x * 256 + tid;
  sh[tid] = (i < n) ? deg[i] : 0;
  __syncthreads();
  for (int s = 128; s > 0; s >>= 1) {
    if (tid < s) sh[tid] += sh[tid + s];
    __syncthreads();
  }
  if (tid == 0) bsum[blockIdx.x] = sh[0];
}

// ---- scan 2: exclusive scan of block sums (nb<=512) ----
__global__ __launch_bounds__(512) void k_scan2(int* __restrict__ bsum, int nb,
                                               int* __restrict__ total_out) {
  __shared__ int sh[512];
  int tid = threadIdx.x;
  int v = (tid < nb) ? bsum[tid] : 0;
  sh[tid] = v;
  __syncthreads();
  for (int off = 1; off < 512; off <<= 1) {
    int t = (tid >= off) ? sh[tid - off] : 0;
    __syncthreads();
    sh[tid] += t;
    __syncthreads();
  }
  if (tid < nb) bsum[tid] = sh[tid] - v;
  if (tid == 0) *total_out = sh[511];
}

// ---- scan 3: rowptr (exclusive) ----
__global__ __launch_bounds__(256) void k_scan3(const int* __restrict__ deg,
                                               const int* __restrict__ bsum,
                                               int* __restrict__ rowptr, int n) {
  __shared__ int sh[256];
  int tid = threadIdx.x;
  int i = blockIdx.x * 256 + tid;
  int v = (i < n) ? deg[i] : 0;
  sh[tid] = v;
  __syncthreads();
  for (int off = 1; off < 256; off <<= 1) {
    int t = (tid >= off) ? sh[tid - off] : 0;
    __syncthreads();
    sh[tid] += t;
    __syncthreads();
  }
  if (i < n) rowptr[i] = bsum[blockIdx.x] + sh[tid] - v;
}

// ---- degree counts -> rsqrt norms ----
__global__ __launch_bounds__(256) void k_norm(unsigned* __restrict__ dego,
                                              unsigned* __restrict__ degi, int n) {
  int i = blockIdx.x * 256 + threadIdx.x;
  if (i >= n) return;
  unsigned a = dego[i];
  dego[i] = __float_as_uint(a ? rsqrtf((float)a) : 0.f);
  unsigned b = degi[i];
  degi[i] = __float_as_uint(b ? rsqrtf((float)b) : 0.f);
}

// ---- destructive CSR fill: idx = atomicAdd(&rowptr[d],1). After this kernel,
// rowptr[d] == end(d); start(d) = d ? rowptr[d-1] : 0. ----
__global__ __launch_bounds__(256) void k_fill(const int* __restrict__ ei, int E, int n,
                                              const int* __restrict__ flag,
                                              int* __restrict__ rowptr,
                                              char* __restrict__ H) {
  int e = blockIdx.x * 256 + threadIdx.x;
  if (e >= E) return;
  int sh = *flag;
  int s = iclamp(ei[(size_t)e << sh], 0, n - 1);
  int d = iclamp(ei[((size_t)E << sh) + ((size_t)e << sh)], 0, n - 1);
  int idx = atomicAdd(&rowptr[d], 1);
  adj_write(H, iclamp(idx, 0, E - 1), s);
}

// ---- S = fp32 x * norm_src -> f16 (SB slot) ----
__global__ __launch_bounds__(256) void k_scale_x(const float* __restrict__ X,
                                                 const unsigned* __restrict__ nsrc,
                                                 char* __restrict__ Sc, int n64) {
  int i = blockIdx.x * 256 + threadIdx.x;
  if (i >= n64) return;
  int r = i >> 6, c = i & 63;
  float ns = __uint_as_float(nsrc[r]);
  float2 v = ((const float2*)X)[i];
  f16x2 o;
  o[0] = (f16)scrub(v.x * ns);
  o[1] = (f16)scrub(v.y * ns);
  *(f16x2*)(Sc + (size_t)r * ROWB + c * 4) = o;
}

// ---- one wave per dst row, 4 neighbors per iteration (16B/lane gather).
// rowptr is the SHIFTED (post-fill) form: start = gw? rp[gw-1]:0, end = rp[gw]. ----
__global__ __launch_bounds__(256) void k_aggregate(const char* __restrict__ H,
                                                   int sinOff, int outOff,
                                                   const int* __restrict__ rowptr,
                                                   const unsigned* __restrict__ ndst,
                                                   int n, int E) {
  int gw = (int)((blockIdx.x * 256u + threadIdx.x) >> 6);
  int lane = threadIdx.x & 63;
  if (gw >= n) return;
  int s = gw ? rowptr[gw - 1] : 0;
  s = iclamp(s, 0, E);
  int e = iclamp(rowptr[gw], s, E);
  const char* Sin = H + sinOff;
  const int grp = lane >> 4;     // 0..3 : which neighbor in the quad
  const int sub = lane & 15;     // 16 lanes x 16B = one 256B S row
  float acc[8] = {0.f, 0.f, 0.f, 0.f, 0.f, 0.f, 0.f, 0.f};
  int i = s;
  // main: 8 neighbors per iteration (two independent quad-loads for ILP)
  for (; i + 8 <= e; i += 8) {
    int nb0 = iclamp(adj_read(H, i + grp), 0, n - 1);
    int nb1 = iclamp(adj_read(H, i + 4 + grp), 0, n - 1);
    f16x8 v0 = *(const f16x8*)(Sin + (size_t)nb0 * ROWB + sub * 16);
    f16x8 v1 = *(const f16x8*)(Sin + (size_t)nb1 * ROWB + sub * 16);
#pragma unroll
    for (int j = 0; j < 8; ++j) acc[j] += (float)v0[j] + (float)v1[j];
  }
  for (; i < e; i += 4) {  // tail: up to 7 neighbors, masked quad
    int idx = i + grp;
    float sc = (idx < e) ? 1.f : 0.f;
    int nb = iclamp(adj_read(H, idx < e ? idx : i), 0, n - 1);
    f16x8 v = *(const f16x8*)(Sin + (size_t)nb * ROWB + sub * 16);
#pragma unroll
    for (int j = 0; j < 8; ++j) acc[j] += sc * (float)v[j];
  }
  // merge the 4 neighbor groups (lane bits 4,5)
#pragma unroll
  for (int j = 0; j < 8; ++j) {
    acc[j] += __shfl_xor(acc[j], 16, 64);
    acc[j] += __shfl_xor(acc[j], 32, 64);
  }
  if (lane < 16) {
    float nd = __uint_as_float(ndst[gw]);
    f16x8 o;
#pragma unroll
    for (int j = 0; j < 8; ++j) o[j] = (f16)scrub(acc[j] * nd);
    *(f16x8*)(((char*)H) + outOff + (size_t)gw * ROWB + lane * 16) = o;
  }
}

// ---- GEMM: C[n,DOUT] = A[n,128] @ W[128,DOUT] + b; A rows strided ROWB (AGG slot).
// W/bias fp32. MID: relu*norm_src -> f16 slot. else: fp32 full row. ----
template <int DOUT, bool MID>
__global__ __launch_bounds__(256) void k_gemm(const char* __restrict__ A,
                                              const float* __restrict__ W,
                                              const float* __restrict__ bias,
                                              const unsigned* __restrict__ nsrc,
                                              char* __restrict__ OUT, int n) {
  extern __shared__ char smem_raw[];
  f16* sB = (f16*)smem_raw;  // W^T swizzled: [DOUT][128]
  const int tid = threadIdx.x;
  for (int idx = tid; idx < 128 * DOUT; idx += 256) {
    int k = idx / DOUT;
    int nn = idx % DOUT;
    int g = (k >> 3) ^ (nn & 15);
    sB[nn * 128 + (g << 3) + (k & 7)] = (f16)scrub(W[idx]);
  }
  __syncthreads();
  const int wave = tid >> 6, lane = tid & 63;
  const int quad = lane >> 4, l16 = lane & 15;
  const int rowbase = blockIdx.x * 128 + wave * 32;
  constexpr int NT = DOUT / 16;
  f32x4 acc[2][NT] = {};
  int r0 = rowbase + l16;      if (r0 > n - 1) r0 = n - 1;
  int r1 = rowbase + 16 + l16; if (r1 > n - 1) r1 = n - 1;
#pragma unroll
  for (int ks = 0; ks < 4; ++ks) {
    const int k0 = ks * 32 + quad * 8;
    const int kg = ks * 4 + quad;
    f16x8 a0 = *(const f16x8*)(A + (size_t)r0 * ROWB + k0 * 2);
    f16x8 a1 = *(const f16x8*)(A + (size_t)r1 * ROWB + k0 * 2);
#pragma unroll
    for (int nt = 0; nt < NT; ++nt) {
      int nn = nt * 16 + l16;
      f16x8 b = *(const f16x8*)(sB + nn * 128 + ((kg ^ l16) << 3));
      acc[0][nt] = __builtin_amdgcn_mfma_f32_16x16x32_f16(a0, b, acc[0][nt], 0, 0, 0);
      acc[1][nt] = __builtin_amdgcn_mfma_f32_16x16x32_f16(a1, b, acc[1][nt], 0, 0, 0);
    }
  }
#pragma unroll
  for (int mt = 0; mt < 2; ++mt) {
#pragma unroll
    for (int r = 0; r < 4; ++r) {
      int row = rowbase + mt * 16 + quad * 4 + r;
      if (row >= n) continue;
      float ns = MID ? __uint_as_float(nsrc[row]) : 1.f;
#pragma unroll
      for (int nt = 0; nt < NT; ++nt) {
        int col = nt * 16 + l16;
        float v = acc[mt][nt][r] + bias[col];
        if (MID) {
          v = scrub(fmaxf(v, 0.f) * ns);
          *(f16*)(OUT + (size_t)row * ROWB + col * 2) = (f16)v;
        } else {
          *(float*)(OUT + (size_t)row * ROWB + col * 4) = scrub(v);
        }
      }
    }
  }
}

// ---- edge_index passthrough as fp32 (bf16-rounded to match ref) ----
__global__ __launch_bounds__(256) void k_edges(const int* __restrict__ ei,
                                               const int* __restrict__ flag,
                                               float* __restrict__ out, int m) {
  int i = blockIdx.x * 256 + threadIdx.x;
  if (i >= m) return;
  int sh = *flag;
  int v = ei[(size_t)i << sh];
  out[i] = bf2f(f2bf((float)v));
}

extern "C" void kernel_launch(void* const* d_in, const int* in_sizes, int n_in,
                              void* d_out, int out_size, void* d_ws, size_t ws_size,
                              hipStream_t stream) {
  const float* X = (const float*)d_in[0];                   // fp32 [N,128]
  const int* EI = (const int*)d_in[1];                      // int32 or int64 (detected)
  const float* W1 = (const float*)d_in[2];
  const float* B1 = (const float*)d_in[3];
  const float* W2 = (const float*)d_in[4];
  const float* B2 = (const float*)d_in[5];
  const float* W3 = (const float*)d_in[6];
  const float* B3 = (const float*)d_in[7];

  const int n = in_sizes[0] / 128;   // 100000
  const int E = in_sizes[1] / 2;     // 1600000

  // tiny workspace (~1.3 MB)
  char* w = (char*)d_ws;
  const size_t nb = ((size_t)n * 4 + 1023) & ~(size_t)1023;
  int* flag        = (int*)(w);
  unsigned* dego   = (unsigned*)(w + 1024);
  unsigned* degi   = (unsigned*)(w + 1024 + nb);
  int* rowptr      = (int*)(w + 1024 + 2 * nb);      // n+1 ints (shifted after fill)
  int* bsum        = (int*)(w + 1024 + 3 * nb);      // <=512 ints

  char* H = (char*)d_out;            // h region: n rows x 1024B (slots + ADJ)

  const int gE = (E + 255) / 256;
  const int gN = (n + 255) / 256;
  const int g64 = (n * 64 + 255) / 256;
  const int gG = (n + 127) / 128;

  hipMemsetAsync(dego, 0, (size_t)n * 4, stream);
  hipMemsetAsync(degi, 0, (size_t)n * 4, stream);

  k_detect<<<1, 64, 0, stream>>>(EI, flag);
  k_degree<<<gE, 256, 0, stream>>>(EI, E, n, flag, dego, degi);
  k_scan1<<<gN, 256, 0, stream>>>((const int*)degi, n, bsum);
  k_scan2<<<1, 512, 0, stream>>>(bsum, gN, rowptr + n);
  k_scan3<<<gN, 256, 0, stream>>>((const int*)degi, bsum, rowptr, n);
  k_fill<<<gE, 256, 0, stream>>>(EI, E, n, flag, rowptr, H);   // shifts rowptr
  k_norm<<<gN, 256, 0, stream>>>(dego, degi, n);

  // layer 1: X -> SB; agg(SB)->AGG; gemm AGG->SA
  k_scale_x<<<g64, 256, 0, stream>>>(X, dego, H + OFF_SB, n * 64);
  k_aggregate<<<g64, 256, 0, stream>>>(H, OFF_SB, OFF_AGG, rowptr, degi, n, E);
  k_gemm<128, true><<<gG, 256, 128 * 128 * 2, stream>>>(H + OFF_AGG, W1, B1, dego,
                                                        H + OFF_SA, n);
  // layer 2: agg(SA)->AGG; gemm AGG->SB
  k_aggregate<<<g64, 256, 0, stream>>>(H, OFF_SA, OFF_AGG, rowptr, degi, n, E);
  k_gemm<128, true><<<gG, 256, 128 * 128 * 2, stream>>>(H + OFF_AGG, W2, B2, dego,
                                                        H + OFF_SB, n);
  // layer 3: agg(SB)->AGG; gemm AGG -> full fp32 rows
  k_aggregate<<<g64, 256, 0, stream>>>(H, OFF_SB, OFF_AGG, rowptr, degi, n, E);
  k_gemm<256, false><<<gG, 256, 256 * 128 * 2, stream>>>(H + OFF_AGG, W3, B3, dego,
                                                         H, n);

  // edges last
  k_edges<<<(2 * E + 255) / 256, 256, 0, stream>>>(
      EI, flag, (float*)d_out + (size_t)n * 256, 2 * E);
}

// Round 7
// 730.958 us; speedup vs baseline: 1.1683x; 1.0262x over previous
//
#include <hip/hip_runtime.h>

typedef _Float16 f16;
typedef _Float16 f16x2 __attribute__((ext_vector_type(2)));
typedef _Float16 f16x8 __attribute__((ext_vector_type(8)));
typedef float f32x2 __attribute__((ext_vector_type(2)));
typedef float f32x4 __attribute__((ext_vector_type(4)));
typedef int i32x4 __attribute__((ext_vector_type(4)));

// d_out h-region: row r owns bytes [r*1024, (r+1)*1024)  (256 fp32 per row).
// Scratch slots while pipeline runs:
//   [0,256)    AGG f16[128]   (MFMA A operand)
//   [256,384)  SA  fp8[128]
//   [384,512)  SB  fp8[128]
//   [768,1024) ADJ int[64]    (CSR adjacency, element i at row i>>6, word i&63)
// Final GEMM overwrites full rows with 256 fp32; edge tail written in degree phase.
#define ROWB 1024
#define OFF_AGG 0
#define OFF_SA 256
#define OFF_SB 384
#define OFF_ADJ 768

__device__ __forceinline__ float bf2f(unsigned short h) {
  return __uint_as_float(((unsigned)h) << 16);
}
__device__ __forceinline__ unsigned short f2bf(float f) {
  unsigned u = __float_as_uint(f);
  u += 0x7fffu + ((u >> 16) & 1u);
  return (unsigned short)(u >> 16);
}
__device__ __forceinline__ float scrub(float v) {        // finite, f16-safe
  if (!(v == v)) return 0.f;
  return fminf(fmaxf(v, -65504.f), 65504.f);
}
__device__ __forceinline__ float scrub8(float v) {       // finite, fp8-safe (fnuz-safe 240)
  if (!(v == v)) return 0.f;
  return fminf(fmaxf(v, -240.f), 240.f);
}
__device__ __forceinline__ int iclamp(int v, int lo, int hi) {
  return v < lo ? lo : (v > hi ? hi : v);
}
__device__ __forceinline__ int adj_read(const char* H, int i) {
  return *(const int*)(H + ((size_t)(i >> 6)) * ROWB + OFF_ADJ + (i & 63) * 4);
}
__device__ __forceinline__ void adj_write(char* H, int i, int v) {
  *(int*)(H + ((size_t)(i >> 6)) * ROWB + OFF_ADJ + (i & 63) * 4) = v;
}
// pack 4 floats -> 4 fp8 bytes
__device__ __forceinline__ int enc4(float a, float b, float c, float d) {
  int w = __builtin_amdgcn_cvt_pk_fp8_f32(a, b, 0, false);
  w = __builtin_amdgcn_cvt_pk_fp8_f32(c, d, w, true);
  return w;
}
// decode 16 fp8 (i32x4) and accumulate into acc[16] with scale sc
__device__ __forceinline__ void dec_acc(i32x4 w, float* acc, float sc) {
#pragma unroll
  for (int d = 0; d < 4; ++d) {
    f32x2 lo = __builtin_amdgcn_cvt_pk_f32_fp8(w[d], false);
    f32x2 hi = __builtin_amdgcn_cvt_pk_f32_fp8(w[d], true);
    acc[d * 4 + 0] += sc * lo[0];
    acc[d * 4 + 1] += sc * lo[1];
    acc[d * 4 + 2] += sc * hi[0];
    acc[d * 4 + 3] += sc * hi[1];
  }
}

// ---- detect edge_index width: int64 => odd int32 words all zero ----
__global__ __launch_bounds__(64) void k_detect(const int* __restrict__ ei,
                                               int* __restrict__ flag) {
  int lane = threadIdx.x;
  int v = ei[2 * lane + 1];
  unsigned long long m = __ballot(v == 0);
  if (lane == 0) *flag = (m == 0xFFFFFFFFFFFFFFFFull) ? 1 : 0;  // 1 = int64
}

// ---- fused: degree histogram (blocks [0,gd)) + edge passthrough (blocks [gd, ...)) ----
__global__ __launch_bounds__(256) void k_degree_edges(const int* __restrict__ ei, int E,
                                                      int n, const int* __restrict__ flag,
                                                      unsigned* __restrict__ dego,
                                                      unsigned* __restrict__ degi,
                                                      float* __restrict__ eout, int gd) {
  const int sh = *flag;
  const int tid = threadIdx.x;
  if ((int)blockIdx.x < gd) {
    const int base = blockIdx.x * 1536 + tid;   // 6 coalesced edges per thread
#pragma unroll
    for (int k = 0; k < 6; ++k) {
      int e = base + k * 256;
      if (e < E) {
        int s = ei[(size_t)e << sh];
        int d = ei[((size_t)E << sh) + ((size_t)e << sh)];
        atomicAdd(&dego[iclamp(s, 0, n - 1)], 1u);
        atomicAdd(&degi[iclamp(d, 0, n - 1)], 1u);
      }
    }
  } else {
    const int m = 2 * E;
    const int base = (blockIdx.x - gd) * 1024 + tid;  // 4 elems per thread
#pragma unroll
    for (int k = 0; k < 4; ++k) {
      int i = base + k * 256;
      if (i < m) {
        int v = ei[(size_t)i << sh];
        eout[i] = bf2f(f2bf((float)v));
      }
    }
  }
}

// ---- scan 1: per-block sums ----
__global__ __launch_bounds__(256) void k_scan1(const int* __restrict__ deg, int n,
                                               int* __restrict__ bsum) {
  __shared__ int sh[256];
  int tid = threadIdx.x;
  int i = blockIdx.x * 256 + tid;
  sh[tid] = (i < n) ? deg[i] : 0;
  __syncthreads();
  for (int s = 128; s > 0; s >>= 1) {
    if (tid < s) sh[tid] += sh[tid + s];
    __syncthreads();
  }
  if (tid == 0) bsum[blockIdx.x] = sh[0];
}

// ---- scan 2: exclusive scan of block sums (nb<=512) ----
__global__ __launch_bounds__(512) void k_scan2(int* __restrict__ bsum, int nb,
                                               int* __restrict__ total_out) {
  __shared__ int sh[512];
  int tid = threadIdx.x;
  int v = (tid < nb) ? bsum[tid] : 0;
  sh[tid] = v;
  __syncthreads();
  for (int off = 1; off < 512; off <<= 1) {
    int t = (tid >= off) ? sh[tid - off] : 0;
    __syncthreads();
    sh[tid] += t;
    __syncthreads();
  }
  if (tid < nb) bsum[tid] = sh[tid] - v;
  if (tid == 0) *total_out = sh[511];
}

// ---- scan 3: rowptr (exclusive) ----
__global__ __launch_bounds__(256) void k_scan3(const int* __restrict__ deg,
                                               const int* __restrict__ bsum,
                                               int* __restrict__ rowptr, int n) {
  __shared__ int sh[256];
  int tid = threadIdx.x;
  int i = blockIdx.x * 256 + tid;
  int v = (i < n) ? deg[i] : 0;
  sh[tid] = v;
  __syncthreads();
  for (int off = 1; off < 256; off <<= 1) {
    int t = (tid >= off) ? sh[tid - off] : 0;
    __syncthreads();
    sh[tid] += t;
    __syncthreads();
  }
  if (i < n) rowptr[i] = bsum[blockIdx.x] + sh[tid] - v;
}

// ---- destructive CSR fill, 4 coalesced edges/thread. After: rowptr[d]==end(d). ----
__global__ __launch_bounds__(256) void k_fill(const int* __restrict__ ei, int E, int n,
                                              const int* __restrict__ flag,
                                              int* __restrict__ rowptr,
                                              char* __restrict__ H) {
  const int sh = *flag;
  const int base = blockIdx.x * 1024 + threadIdx.x;
#pragma unroll
  for (int k = 0; k < 4; ++k) {
    int e = base + k * 256;
    if (e < E) {
      int s = iclamp(ei[(size_t)e << sh], 0, n - 1);
      int d = iclamp(ei[((size_t)E << sh) + ((size_t)e << sh)], 0, n - 1);
      int idx = atomicAdd(&rowptr[d], 1);
      adj_write(H, iclamp(idx, 0, E - 1), s);
    }
  }
}

// ---- fused: degree counts -> rsqrt norms (global) + S = x*norm_src -> fp8 SB ----
__global__ __launch_bounds__(256) void k_norm_scale(const float* __restrict__ X,
                                                    unsigned* __restrict__ dego,
                                                    unsigned* __restrict__ degi,
                                                    char* __restrict__ H, int n) {
  __shared__ float ns[256];
  const int tid = threadIdx.x;
  const int rb = blockIdx.x * 256;
  int r = rb + tid;
  float f = 0.f;
  if (r < n) {
    unsigned a = dego[r];
    f = a ? rsqrtf((float)a) : 0.f;
    dego[r] = __float_as_uint(f);
    unsigned b = degi[r];
    degi[r] = __float_as_uint(b ? rsqrtf((float)b) : 0.f);
  }
  ns[tid] = f;
  __syncthreads();
  const int nrow = (n - rb < 256) ? (n - rb) : 256;
  for (int q = tid; q < nrow * 32; q += 256) {
    int lr = q >> 5, c = q & 31;
    int row = rb + lr;
    float4 v = ((const float4*)X)[(size_t)row * 32 + c];
    float s = ns[lr];
    int w = enc4(scrub8(v.x * s), scrub8(v.y * s), scrub8(v.z * s), scrub8(v.w * s));
    *(int*)(H + (size_t)row * ROWB + OFF_SB + c * 4) = w;
  }
}

// ---- one wave per dst row; fp8 input rows (128B), 8 neighbors per wave-load.
// rowptr is SHIFTED (post-fill): start = gw? rp[gw-1]:0, end = rp[gw].
// Output: AGG slot, f16[128]. ----
__global__ __launch_bounds__(256) void k_aggregate(const char* __restrict__ H,
                                                   int sinOff,
                                                   const int* __restrict__ rowptr,
                                                   const unsigned* __restrict__ ndst,
                                                   int n, int E) {
  int gw = (int)((blockIdx.x * 256u + threadIdx.x) >> 6);
  int lane = threadIdx.x & 63;
  if (gw >= n) return;
  int s = gw ? rowptr[gw - 1] : 0;
  s = iclamp(s, 0, E);
  int e = iclamp(rowptr[gw], s, E);
  const char* Sin = H + sinOff;
  const int grp = lane >> 3;   // 0..7 : neighbor within the octet
  const int sub = lane & 7;    // 8 lanes x 16B = one 128B fp8 row
  float acc[16] = {};
  int i = s;
  for (; i + 16 <= e; i += 16) {   // 16 neighbors per iter (2 independent loads)
    int nb0 = iclamp(adj_read(H, i + grp), 0, n - 1);
    int nb1 = iclamp(adj_read(H, i + 8 + grp), 0, n - 1);
    i32x4 w0 = *(const i32x4*)(Sin + (size_t)nb0 * ROWB + sub * 16);
    i32x4 w1 = *(const i32x4*)(Sin + (size_t)nb1 * ROWB + sub * 16);
    dec_acc(w0, acc, 1.f);
    dec_acc(w1, acc, 1.f);
  }
  for (; i < e; i += 8) {          // masked tail, up to 15 neighbors
    int idx = i + grp;
    float sc = (idx < e) ? 1.f : 0.f;
    int nb = iclamp(adj_read(H, idx < e ? idx : i), 0, n - 1);
    i32x4 w = *(const i32x4*)(Sin + (size_t)nb * ROWB + sub * 16);
    dec_acc(w, acc, sc);
  }
  // merge the 8 neighbor groups (lane bits 3,4,5)
#pragma unroll
  for (int j = 0; j < 16; ++j) {
    acc[j] += __shfl_xor(acc[j], 8, 64);
    acc[j] += __shfl_xor(acc[j], 16, 64);
    acc[j] += __shfl_xor(acc[j], 32, 64);
  }
  if (lane < 8) {
    float nd = __uint_as_float(ndst[gw]);
    f16x8 o0, o1;
#pragma unroll
    for (int j = 0; j < 8; ++j) {
      o0[j] = (f16)scrub(acc[j] * nd);
      o1[j] = (f16)scrub(acc[8 + j] * nd);
    }
    char* dst = ((char*)H) + OFF_AGG + (size_t)gw * ROWB + lane * 32;
    *(f16x8*)dst = o0;
    *(f16x8*)(dst + 16) = o1;
  }
}

// ---- GEMM: C[n,DOUT] = A[n,128] @ W[128,DOUT] + b; A = f16 AGG slot (stride ROWB).
// MID: relu*norm_src -> fp8 slot (1B/elem). else: fp32 full row. ----
template <int DOUT, bool MID>
__global__ __launch_bounds__(256) void k_gemm(const char* __restrict__ A,
                                              const float* __restrict__ W,
                                              const float* __restrict__ bias,
                                              const unsigned* __restrict__ nsrc,
                                              char* __restrict__ OUT, int n) {
  extern __shared__ char smem_raw[];
  f16* sB = (f16*)smem_raw;  // W^T swizzled: [DOUT][128]
  const int tid = threadIdx.x;
  for (int idx = tid; idx < 128 * DOUT; idx += 256) {
    int k = idx / DOUT;
    int nn = idx % DOUT;
    int g = (k >> 3) ^ (nn & 15);
    sB[nn * 128 + (g << 3) + (k & 7)] = (f16)scrub(W[idx]);
  }
  __syncthreads();
  const int wave = tid >> 6, lane = tid & 63;
  const int quad = lane >> 4, l16 = lane & 15;
  const int rowbase = blockIdx.x * 128 + wave * 32;
  constexpr int NT = DOUT / 16;
  f32x4 acc[2][NT] = {};
  int r0 = rowbase + l16;      if (r0 > n - 1) r0 = n - 1;
  int r1 = rowbase + 16 + l16; if (r1 > n - 1) r1 = n - 1;
#pragma unroll
  for (int ks = 0; ks < 4; ++ks) {
    const int k0 = ks * 32 + quad * 8;
    const int kg = ks * 4 + quad;
    f16x8 a0 = *(const f16x8*)(A + (size_t)r0 * ROWB + k0 * 2);
    f16x8 a1 = *(const f16x8*)(A + (size_t)r1 * ROWB + k0 * 2);
#pragma unroll
    for (int nt = 0; nt < NT; ++nt) {
      int nn = nt * 16 + l16;
      f16x8 b = *(const f16x8*)(sB + nn * 128 + ((kg ^ l16) << 3));
      acc[0][nt] = __builtin_amdgcn_mfma_f32_16x16x32_f16(a0, b, acc[0][nt], 0, 0, 0);
      acc[1][nt] = __builtin_amdgcn_mfma_f32_16x16x32_f16(a1, b, acc[1][nt], 0, 0, 0);
    }
  }
#pragma unroll
  for (int mt = 0; mt < 2; ++mt) {
#pragma unroll
    for (int r = 0; r < 4; ++r) {
      int row = rowbase + mt * 16 + quad * 4 + r;
      if (row >= n) continue;
      float ns = MID ? __uint_as_float(nsrc[row]) : 1.f;
#pragma unroll
      for (int nt = 0; nt < NT; ++nt) {
        int col = nt * 16 + l16;
        float v = acc[mt][nt][r] + bias[col];
        if (MID) {
          v = fminf(fmaxf(v, 0.f) * ns, 240.f);
          if (!(v == v)) v = 0.f;
          int w8 = __builtin_amdgcn_cvt_pk_fp8_f32(v, v, 0, false);
          *(unsigned char*)(OUT + (size_t)row * ROWB + col) = (unsigned char)(w8 & 0xff);
        } else {
          *(float*)(OUT + (size_t)row * ROWB + col * 4) = scrub(v);
        }
      }
    }
  }
}

extern "C" void kernel_launch(void* const* d_in, const int* in_sizes, int n_in,
                              void* d_out, int out_size, void* d_ws, size_t ws_size,
                              hipStream_t stream) {
  const float* X = (const float*)d_in[0];                   // fp32 [N,128]
  const int* EI = (const int*)d_in[1];                      // int32 or int64 (detected)
  const float* W1 = (const float*)d_in[2];
  const float* B1 = (const float*)d_in[3];
  const float* W2 = (const float*)d_in[4];
  const float* B2 = (const float*)d_in[5];
  const float* W3 = (const float*)d_in[6];
  const float* B3 = (const float*)d_in[7];

  const int n = in_sizes[0] / 128;   // 100000
  const int E = in_sizes[1] / 2;     // 1600000

  // tiny workspace (~1.3 MB)
  char* w = (char*)d_ws;
  const size_t nb = ((size_t)n * 4 + 1023) & ~(size_t)1023;
  int* flag        = (int*)(w);
  unsigned* dego   = (unsigned*)(w + 1024);
  unsigned* degi   = (unsigned*)(w + 1024 + nb);
  int* rowptr      = (int*)(w + 1024 + 2 * nb);      // n+1 ints (shifted after fill)
  int* bsum        = (int*)(w + 1024 + 3 * nb);      // <=512 ints

  char* H = (char*)d_out;            // h region: n rows x 1024B (slots + ADJ)

  const int gd = (E + 1535) / 1536;          // degree blocks (6 edges/thread)
  const int ge = (2 * E + 1023) / 1024;      // edge-copy blocks (4 elems/thread)
  const int gf = (E + 1023) / 1024;          // fill blocks (4 edges/thread)
  const int gN = (n + 255) / 256;
  const int g64 = (n * 64 + 255) / 256;
  const int gG = (n + 127) / 128;

  hipMemsetAsync(dego, 0, (size_t)n * 4, stream);
  hipMemsetAsync(degi, 0, (size_t)n * 4, stream);

  k_detect<<<1, 64, 0, stream>>>(EI, flag);
  k_degree_edges<<<gd + ge, 256, 0, stream>>>(EI, E, n, flag, dego, degi,
                                              (float*)d_out + (size_t)n * 256, gd);
  k_scan1<<<gN, 256, 0, stream>>>((const int*)degi, n, bsum);
  k_scan2<<<1, 512, 0, stream>>>(bsum, gN, rowptr + n);
  k_scan3<<<gN, 256, 0, stream>>>((const int*)degi, bsum, rowptr, n);
  k_fill<<<gf, 256, 0, stream>>>(EI, E, n, flag, rowptr, H);   // shifts rowptr
  k_norm_scale<<<gN, 256, 0, stream>>>(X, dego, degi, H, n);   // norms + SB (fp8)

  // layer 1: agg(SB)->AGG; gemm AGG->SA (fp8)
  k_aggregate<<<g64, 256, 0, stream>>>(H, OFF_SB, rowptr, degi, n, E);
  k_gemm<128, true><<<gG, 256, 128 * 128 * 2, stream>>>(H + OFF_AGG, W1, B1, dego,
                                                        H + OFF_SA, n);
  // layer 2: agg(SA)->AGG; gemm AGG->SB (fp8)
  k_aggregate<<<g64, 256, 0, stream>>>(H, OFF_SA, rowptr, degi, n, E);
  k_gemm<128, true><<<gG, 256, 128 * 128 * 2, stream>>>(H + OFF_AGG, W2, B2, dego,
                                                        H + OFF_SB, n);
  // layer 3: agg(SB)->AGG; gemm AGG -> full fp32 rows
  k_aggregate<<<g64, 256, 0, stream>>>(H, OFF_SB, rowptr, degi, n, E);
  k_gemm<256, false><<<gG, 256, 256 * 128 * 2, stream>>>(H + OFF_AGG, W3, B3, dego,
                                                         H, n);
}

// Round 8
// 688.360 us; speedup vs baseline: 1.2406x; 1.0619x over previous
//
#include <hip/hip_runtime.h>

typedef _Float16 f16;
typedef _Float16 f16x8 __attribute__((ext_vector_type(8)));
typedef float f32x2 __attribute__((ext_vector_type(2)));
typedef float f32x4 __attribute__((ext_vector_type(4)));
typedef int i32x4 __attribute__((ext_vector_type(4)));

// d_out h-region: row r owns bytes [r*1024, (r+1)*1024)  (256 fp32 per row).
// Scratch slots while pipeline runs:
//   [0,256)    AGG f16[128]   (MFMA A operand)
//   [256,384)  SA  fp8[128]
//   [384,512)  SB  fp8[128]
//   [512,768)  K   int[64]    (edge e's within-dst rank, element e at row e>>6)
//   [768,1024) ADJ int[64]    (CSR adjacency, element i at row i>>6, word i&63)
// Final GEMM overwrites full rows with 256 fp32; edge tail written in degree phase.
#define ROWB 1024
#define OFF_AGG 0
#define OFF_SA 256
#define OFF_SB 384
#define OFF_K 512
#define OFF_ADJ 768

__device__ __forceinline__ float bf2f(unsigned short h) {
  return __uint_as_float(((unsigned)h) << 16);
}
__device__ __forceinline__ unsigned short f2bf(float f) {
  unsigned u = __float_as_uint(f);
  u += 0x7fffu + ((u >> 16) & 1u);
  return (unsigned short)(u >> 16);
}
__device__ __forceinline__ float scrub(float v) {        // finite, f16-safe
  if (!(v == v)) return 0.f;
  return fminf(fmaxf(v, -65504.f), 65504.f);
}
__device__ __forceinline__ float scrub8(float v) {       // finite, fp8-safe
  if (!(v == v)) return 0.f;
  return fminf(fmaxf(v, -240.f), 240.f);
}
__device__ __forceinline__ int iclamp(int v, int lo, int hi) {
  return v < lo ? lo : (v > hi ? hi : v);
}
__device__ __forceinline__ int adj_read(const char* H, int i) {
  return *(const int*)(H + ((size_t)(i >> 6)) * ROWB + OFF_ADJ + (i & 63) * 4);
}
__device__ __forceinline__ void adj_write(char* H, int i, int v) {
  *(int*)(H + ((size_t)(i >> 6)) * ROWB + OFF_ADJ + (i & 63) * 4) = v;
}
__device__ __forceinline__ int enc4(float a, float b, float c, float d) {
  int w = __builtin_amdgcn_cvt_pk_fp8_f32(a, b, 0, false);
  w = __builtin_amdgcn_cvt_pk_fp8_f32(c, d, w, true);
  return w;
}
__device__ __forceinline__ void dec_acc(i32x4 w, float* acc, float sc) {
#pragma unroll
  for (int d = 0; d < 4; ++d) {
    f32x2 lo = __builtin_amdgcn_cvt_pk_f32_fp8(w[d], false);
    f32x2 hi = __builtin_amdgcn_cvt_pk_f32_fp8(w[d], true);
    acc[d * 4 + 0] += sc * lo[0];
    acc[d * 4 + 1] += sc * lo[1];
    acc[d * 4 + 2] += sc * hi[0];
    acc[d * 4 + 3] += sc * hi[1];
  }
}

// ---- detect edge_index width: int64 => odd int32 words all zero ----
__global__ __launch_bounds__(64) void k_detect(const int* __restrict__ ei,
                                               int* __restrict__ flag) {
  int lane = threadIdx.x;
  int v = ei[2 * lane + 1];
  unsigned long long m = __ballot(v == 0);
  if (lane == 0) *flag = (m == 0xFFFFFFFFFFFFFFFFull) ? 1 : 0;  // 1 = int64
}

// ---- fused: degree histogram + per-edge dst-rank K (blocks [0,gd)) and
//      edge passthrough (blocks [gd,...)) ----
__global__ __launch_bounds__(256) void k_degree_edges(const int* __restrict__ ei, int E,
                                                      int n, const int* __restrict__ flag,
                                                      unsigned* __restrict__ dego,
                                                      unsigned* __restrict__ degi,
                                                      float* __restrict__ eout,
                                                      char* __restrict__ H, int gd) {
  const int sh = *flag;
  const int tid = threadIdx.x;
  if ((int)blockIdx.x < gd) {
    const int base = blockIdx.x * 1536 + tid;   // 6 coalesced edges per thread
#pragma unroll
    for (int k = 0; k < 6; ++k) {
      int e = base + k * 256;
      if (e < E) {
        int s = iclamp(ei[(size_t)e << sh], 0, n - 1);
        int d = iclamp(ei[((size_t)E << sh) + ((size_t)e << sh)], 0, n - 1);
        atomicAdd(&dego[s], 1u);
        int rk = (int)atomicAdd(&degi[d], 1u);  // within-dst rank
        *(int*)(H + ((size_t)(e >> 6)) * ROWB + OFF_K + (e & 63) * 4) = rk;
      }
    }
  } else {
    const int m = 2 * E;
    const int base = (blockIdx.x - gd) * 1024 + tid;  // 4 elems per thread
#pragma unroll
    for (int k = 0; k < 4; ++k) {
      int i = base + k * 256;
      if (i < m) {
        int v = ei[(size_t)i << sh];
        eout[i] = bf2f(f2bf((float)v));
      }
    }
  }
}

// ---- scan 1: per-block sums ----
__global__ __launch_bounds__(256) void k_scan1(const int* __restrict__ deg, int n,
                                               int* __restrict__ bsum) {
  __shared__ int sh[256];
  int tid = threadIdx.x;
  int i = blockIdx.x * 256 + tid;
  sh[tid] = (i < n) ? deg[i] : 0;
  __syncthreads();
  for (int s = 128; s > 0; s >>= 1) {
    if (tid < s) sh[tid] += sh[tid + s];
    __syncthreads();
  }
  if (tid == 0) bsum[blockIdx.x] = sh[0];
}

// ---- scan 2: exclusive scan of block sums (nb<=512) ----
__global__ __launch_bounds__(512) void k_scan2(int* __restrict__ bsum, int nb,
                                               int* __restrict__ total_out) {
  __shared__ int sh[512];
  int tid = threadIdx.x;
  int v = (tid < nb) ? bsum[tid] : 0;
  sh[tid] = v;
  __syncthreads();
  for (int off = 1; off < 512; off <<= 1) {
    int t = (tid >= off) ? sh[tid - off] : 0;
    __syncthreads();
    sh[tid] += t;
    __syncthreads();
  }
  if (tid < nb) bsum[tid] = sh[tid] - v;
  if (tid == 0) *total_out = sh[511];
}

// ---- scan 3: rowptr (exclusive) ----
__global__ __launch_bounds__(256) void k_scan3(const int* __restrict__ deg,
                                               const int* __restrict__ bsum,
                                               int* __restrict__ rowptr, int n) {
  __shared__ int sh[256];
  int tid = threadIdx.x;
  int i = blockIdx.x * 256 + tid;
  int v = (i < n) ? deg[i] : 0;
  sh[tid] = v;
  __syncthreads();
  for (int off = 1; off < 256; off <<= 1) {
    int t = (tid >= off) ? sh[tid - off] : 0;
    __syncthreads();
    sh[tid] += t;
    __syncthreads();
  }
  if (i < n) rowptr[i] = bsum[blockIdx.x] + sh[tid] - v;
}

// ---- fused: CSR fill (no atomics; blocks [0,gf)) + norms + X->fp8 SB (blocks [gf,...)) ----
__global__ __launch_bounds__(256) void k_fill_normscale(const int* __restrict__ ei, int E,
                                                        int n, const int* __restrict__ flag,
                                                        const int* __restrict__ rowptr,
                                                        unsigned* __restrict__ dego,
                                                        unsigned* __restrict__ degi,
                                                        const float* __restrict__ X,
                                                        char* __restrict__ H, int gf) {
  __shared__ float ns[256];
  const int tid = threadIdx.x;
  if ((int)blockIdx.x < gf) {
    const int sh = *flag;
    const int base = blockIdx.x * 1024 + tid;   // 4 coalesced edges/thread
#pragma unroll
    for (int k = 0; k < 4; ++k) {
      int e = base + k * 256;
      if (e < E) {
        int s = iclamp(ei[(size_t)e << sh], 0, n - 1);
        int d = iclamp(ei[((size_t)E << sh) + ((size_t)e << sh)], 0, n - 1);
        int rk = *(const int*)(H + ((size_t)(e >> 6)) * ROWB + OFF_K + (e & 63) * 4);
        int idx = iclamp(rowptr[d] + rk, 0, E - 1);
        adj_write(H, idx, s);
      }
    }
  } else {
    const int rb = (blockIdx.x - gf) * 256;
    int r = rb + tid;
    float f = 0.f;
    if (r < n) {
      unsigned a = dego[r];
      f = a ? rsqrtf((float)a) : 0.f;
      dego[r] = __float_as_uint(f);
      unsigned b = degi[r];
      degi[r] = __float_as_uint(b ? rsqrtf((float)b) : 0.f);
    }
    ns[tid] = f;
    __syncthreads();
    const int nrow = (n - rb < 256) ? (n - rb) : 256;
    for (int q = tid; q < nrow * 32; q += 256) {
      int lr = q >> 5, c = q & 31;
      int row = rb + lr;
      float4 v = ((const float4*)X)[(size_t)row * 32 + c];
      float s = ns[lr];
      int w = enc4(scrub8(v.x * s), scrub8(v.y * s), scrub8(v.z * s), scrub8(v.w * s));
      *(int*)(H + (size_t)row * ROWB + OFF_SB + c * 4) = w;
    }
  }
}

// ---- 2 dst rows per wave; fp8 input rows (128B), 8 neighbors per wave-load.
// rowptr is exclusive: start=rp[gw], end=rp[gw+1]. Output: AGG slot f16[128]. ----
__global__ __launch_bounds__(256) void k_aggregate(const char* __restrict__ H,
                                                   int sinOff,
                                                   const int* __restrict__ rowptr,
                                                   const unsigned* __restrict__ ndst,
                                                   int n, int E) {
  const int wv = blockIdx.x * 4 + (threadIdx.x >> 6);
  const int lane = threadIdx.x & 63;
  const int gw0 = wv * 2, gw1 = gw0 + 1;
  if (gw0 >= n) return;
  int s0 = iclamp(rowptr[gw0], 0, E);
  int e0 = iclamp(rowptr[gw0 + 1], s0, E);
  const bool has1 = (gw1 < n);
  int s1 = has1 ? iclamp(rowptr[gw1], 0, E) : 0;
  int e1 = has1 ? iclamp(rowptr[gw1 + 1], s1, E) : 0;
  const char* Sin = H + sinOff;
  const int grp = lane >> 3;   // neighbor within octet
  const int sub = lane & 7;    // 8 lanes x 16B = one 128B fp8 row
  float a0[16] = {}, a1[16] = {};
  int i0 = s0, i1 = s1;
  // joint main: both rows' loads in flight together
  while (i0 + 8 <= e0 && i1 + 8 <= e1) {
    int nA = iclamp(adj_read(H, i0 + grp), 0, n - 1);
    int nB = iclamp(adj_read(H, i1 + grp), 0, n - 1);
    i32x4 wA = *(const i32x4*)(Sin + (size_t)nA * ROWB + sub * 16);
    i32x4 wB = *(const i32x4*)(Sin + (size_t)nB * ROWB + sub * 16);
    dec_acc(wA, a0, 1.f);
    dec_acc(wB, a1, 1.f);
    i0 += 8;
    i1 += 8;
  }
  for (; i0 + 8 <= e0; i0 += 8) {
    int nA = iclamp(adj_read(H, i0 + grp), 0, n - 1);
    i32x4 wA = *(const i32x4*)(Sin + (size_t)nA * ROWB + sub * 16);
    dec_acc(wA, a0, 1.f);
  }
  for (; i1 + 8 <= e1; i1 += 8) {
    int nB = iclamp(adj_read(H, i1 + grp), 0, n - 1);
    i32x4 wB = *(const i32x4*)(Sin + (size_t)nB * ROWB + sub * 16);
    dec_acc(wB, a1, 1.f);
  }
  for (; i0 < e0; i0 += 8) {   // masked tails
    int idx = i0 + grp;
    float sc = (idx < e0) ? 1.f : 0.f;
    int nb = iclamp(adj_read(H, idx < e0 ? idx : i0), 0, n - 1);
    i32x4 w = *(const i32x4*)(Sin + (size_t)nb * ROWB + sub * 16);
    dec_acc(w, a0, sc);
  }
  for (; i1 < e1; i1 += 8) {
    int idx = i1 + grp;
    float sc = (idx < e1) ? 1.f : 0.f;
    int nb = iclamp(adj_read(H, idx < e1 ? idx : i1), 0, n - 1);
    i32x4 w = *(const i32x4*)(Sin + (size_t)nb * ROWB + sub * 16);
    dec_acc(w, a1, sc);
  }
  // merge 8 neighbor groups (bits 3,4,5) — results valid in ALL lanes
#pragma unroll
  for (int j = 0; j < 16; ++j) {
    a0[j] += __shfl_xor(a0[j], 8, 64);
    a0[j] += __shfl_xor(a0[j], 16, 64);
    a0[j] += __shfl_xor(a0[j], 32, 64);
    a1[j] += __shfl_xor(a1[j], 8, 64);
    a1[j] += __shfl_xor(a1[j], 16, 64);
    a1[j] += __shfl_xor(a1[j], 32, 64);
  }
  if (lane < 8) {            // lanes 0-7: store row0
    float nd = __uint_as_float(ndst[gw0]);
    f16x8 o0, o1;
#pragma unroll
    for (int j = 0; j < 8; ++j) {
      o0[j] = (f16)scrub(a0[j] * nd);
      o1[j] = (f16)scrub(a0[8 + j] * nd);
    }
    char* dst = ((char*)H) + OFF_AGG + (size_t)gw0 * ROWB + lane * 32;
    *(f16x8*)dst = o0;
    *(f16x8*)(dst + 16) = o1;
  } else if (lane < 16 && has1) {  // lanes 8-15: store row1
    int l = lane & 7;
    float nd = __uint_as_float(ndst[gw1]);
    f16x8 o0, o1;
#pragma unroll
    for (int j = 0; j < 8; ++j) {
      o0[j] = (f16)scrub(a1[j] * nd);
      o1[j] = (f16)scrub(a1[8 + j] * nd);
    }
    char* dst = ((char*)H) + OFF_AGG + (size_t)gw1 * ROWB + l * 32;
    *(f16x8*)dst = o0;
    *(f16x8*)(dst + 16) = o1;
  }
}

// ---- GEMM: C[n,DOUT] = A[n,128] @ W[128,DOUT] + b; A = f16 AGG slot (stride ROWB).
// MID: relu*norm_src -> fp8 slot. else: fp32 full row. ----
template <int DOUT, bool MID>
__global__ __launch_bounds__(256) void k_gemm(const char* __restrict__ A,
                                              const float* __restrict__ W,
                                              const float* __restrict__ bias,
                                              const unsigned* __restrict__ nsrc,
                                              char* __restrict__ OUT, int n) {
  extern __shared__ char smem_raw[];
  f16* sB = (f16*)smem_raw;  // W^T swizzled: [DOUT][128]
  const int tid = threadIdx.x;
  for (int idx = tid; idx < 128 * DOUT; idx += 256) {
    int k = idx / DOUT;
    int nn = idx % DOUT;
    int g = (k >> 3) ^ (nn & 15);
    sB[nn * 128 + (g << 3) + (k & 7)] = (f16)scrub(W[idx]);
  }
  __syncthreads();
  const int wave = tid >> 6, lane = tid & 63;
  const int quad = lane >> 4, l16 = lane & 15;
  const int rowbase = blockIdx.x * 128 + wave * 32;
  constexpr int NT = DOUT / 16;
  f32x4 acc[2][NT] = {};
  int r0 = rowbase + l16;      if (r0 > n - 1) r0 = n - 1;
  int r1 = rowbase + 16 + l16; if (r1 > n - 1) r1 = n - 1;
#pragma unroll
  for (int ks = 0; ks < 4; ++ks) {
    const int k0 = ks * 32 + quad * 8;
    const int kg = ks * 4 + quad;
    f16x8 a0 = *(const f16x8*)(A + (size_t)r0 * ROWB + k0 * 2);
    f16x8 a1 = *(const f16x8*)(A + (size_t)r1 * ROWB + k0 * 2);
#pragma unroll
    for (int nt = 0; nt < NT; ++nt) {
      int nn = nt * 16 + l16;
      f16x8 b = *(const f16x8*)(sB + nn * 128 + ((kg ^ l16) << 3));
      acc[0][nt] = __builtin_amdgcn_mfma_f32_16x16x32_f16(a0, b, acc[0][nt], 0, 0, 0);
      acc[1][nt] = __builtin_amdgcn_mfma_f32_16x16x32_f16(a1, b, acc[1][nt], 0, 0, 0);
    }
  }
#pragma unroll
  for (int mt = 0; mt < 2; ++mt) {
#pragma unroll
    for (int r = 0; r < 4; ++r) {
      int row = rowbase + mt * 16 + quad * 4 + r;
      if (row >= n) continue;
      float ns = MID ? __uint_as_float(nsrc[row]) : 1.f;
#pragma unroll
      for (int nt = 0; nt < NT; ++nt) {
        int col = nt * 16 + l16;
        float v = acc[mt][nt][r] + bias[col];
        if (MID) {
          v = fminf(fmaxf(v, 0.f) * ns, 240.f);
          if (!(v == v)) v = 0.f;
          int w8 = __builtin_amdgcn_cvt_pk_fp8_f32(v, v, 0, false);
          *(unsigned char*)(OUT + (size_t)row * ROWB + col) = (unsigned char)(w8 & 0xff);
        } else {
          *(float*)(OUT + (size_t)row * ROWB + col * 4) = scrub(v);
        }
      }
    }
  }
}

extern "C" void kernel_launch(void* const* d_in, const int* in_sizes, int n_in,
                              void* d_out, int out_size, void* d_ws, size_t ws_size,
                              hipStream_t stream) {
  const float* X = (const float*)d_in[0];                   // fp32 [N,128]
  const int* EI = (const int*)d_in[1];                      // int32 or int64 (detected)
  const float* W1 = (const float*)d_in[2];
  const float* B1 = (const float*)d_in[3];
  const float* W2 = (const float*)d_in[4];
  const float* B2 = (const float*)d_in[5];
  const float* W3 = (const float*)d_in[6];
  const float* B3 = (const float*)d_in[7];

  const int n = in_sizes[0] / 128;   // 100000
  const int E = in_sizes[1] / 2;     // 1600000

  // tiny workspace (~1.3 MB)
  char* w = (char*)d_ws;
  const size_t nb = ((size_t)n * 4 + 1023) & ~(size_t)1023;
  int* flag        = (int*)(w);
  unsigned* dego   = (unsigned*)(w + 1024);
  unsigned* degi   = (unsigned*)(w + 1024 + nb);
  int* rowptr      = (int*)(w + 1024 + 2 * nb);      // n+1 ints (exclusive)
  int* bsum        = (int*)(w + 1024 + 3 * nb);      // <=512 ints

  char* H = (char*)d_out;            // h region: n rows x 1024B (slots + K + ADJ)

  const int gd = (E + 1535) / 1536;          // degree blocks (6 edges/thread)
  const int ge = (2 * E + 1023) / 1024;      // edge-copy blocks (4 elems/thread)
  const int gf = (E + 1023) / 1024;          // fill blocks (4 edges/thread)
  const int gN = (n + 255) / 256;
  const int g2 = (n + 7) / 8;                // aggregate: 8 rows per block (2/wave)
  const int gG = (n + 127) / 128;

  hipMemsetAsync(dego, 0, (size_t)n * 4, stream);
  hipMemsetAsync(degi, 0, (size_t)n * 4, stream);

  k_detect<<<1, 64, 0, stream>>>(EI, flag);
  k_degree_edges<<<gd + ge, 256, 0, stream>>>(EI, E, n, flag, dego, degi,
                                              (float*)d_out + (size_t)n * 256, H, gd);
  k_scan1<<<gN, 256, 0, stream>>>((const int*)degi, n, bsum);
  k_scan2<<<1, 512, 0, stream>>>(bsum, gN, rowptr + n);
  k_scan3<<<gN, 256, 0, stream>>>((const int*)degi, bsum, rowptr, n);
  k_fill_normscale<<<gf + gN, 256, 0, stream>>>(EI, E, n, flag, rowptr, dego, degi,
                                                X, H, gf);

  // layer 1: agg(SB)->AGG; gemm AGG->SA (fp8)
  k_aggregate<<<g2, 256, 0, stream>>>(H, OFF_SB, rowptr, degi, n, E);
  k_gemm<128, true><<<gG, 256, 128 * 128 * 2, stream>>>(H + OFF_AGG, W1, B1, dego,
                                                        H + OFF_SA, n);
  // layer 2: agg(SA)->AGG; gemm AGG->SB (fp8)
  k_aggregate<<<g2, 256, 0, stream>>>(H, OFF_SA, rowptr, degi, n, E);
  k_gemm<128, true><<<gG, 256, 128 * 128 * 2, stream>>>(H + OFF_AGG, W2, B2, dego,
                                                        H + OFF_SB, n);
  // layer 3: agg(SB)->AGG; gemm AGG -> full fp32 rows
  k_aggregate<<<g2, 256, 0, stream>>>(H, OFF_SB, rowptr, degi, n, E);
  k_gemm<256, false><<<gG, 256, 256 * 128 * 2, stream>>>(H + OFF_AGG, W3, B3, dego,
                                                         H, n);
}